// Round 3
// baseline (1095.610 us; speedup 1.0000x reference)
//
#include <hip/hip_runtime.h>
#include <cstdint>
#include <cstddef>

// ---------------- problem constants ----------------
#define HD    1024
#define FD    4096
#define NE    8
#define NTOK  4096            // 2*2048
#define CAP   1280            // ceil(2*1.25*4096/8)
#define NSLOT (NE*CAP)        // 10240 expert slots
#define TOTSLOT (NSLOT+NTOK)  // + shared rows

typedef float    f32x4  __attribute__((ext_vector_type(4)));
typedef float    f32x2  __attribute__((ext_vector_type(2)));
typedef _Float16 f16x8  __attribute__((ext_vector_type(8)));
typedef _Float16 f16x4  __attribute__((ext_vector_type(4)));

typedef __attribute__((address_space(3))) unsigned int as3_u32;
typedef __attribute__((address_space(1))) unsigned int as1_u32;

__device__ __forceinline__ void load_lds16(const _Float16* g, _Float16* l) {
  __builtin_amdgcn_global_load_lds((const as1_u32*)g, (as3_u32*)l, 16, 0, 0);
}

// ---------------- 1) weight convert+transpose + x convert ----------------------
__global__ __launch_bounds__(512) void transpose_cvt(
    const float* __restrict__ w1, const float* __restrict__ w2,
    const float* __restrict__ sw1, const float* __restrict__ sw2,
    const float* __restrict__ x,
    _Float16* __restrict__ w1t, _Float16* __restrict__ w2t,
    _Float16* __restrict__ sw1t, _Float16* __restrict__ sw2t,
    _Float16* __restrict__ x16)
{
  int b = blockIdx.x;
  int tid = threadIdx.x;
  if (b >= 4608) {                       // x: 4096*1024 f32 -> f16, 256 blocks
    int cb = b - 4608;
    #pragma unroll
    for (int it = 0; it < 8; ++it) {
      size_t i = (size_t)cb*16384 + (size_t)(it*512 + tid)*4;
      f32x4 v = *(const f32x4*)(x + i);
      f16x4 h; h[0]=(_Float16)v[0]; h[1]=(_Float16)v[1]; h[2]=(_Float16)v[2]; h[3]=(_Float16)v[3];
      *(f16x4*)(x16 + i) = h;
    }
    return;
  }
  const float* src; _Float16* dst; int R, C;
  if (b < 2048)      { int e = b>>8;        src = w1 + (size_t)e*HD*FD; dst = w1t + (size_t)e*FD*HD; R=HD; C=FD; }
  else if (b < 4096) { int e = (b-2048)>>8; src = w2 + (size_t)e*FD*HD; dst = w2t + (size_t)e*HD*FD; R=FD; C=HD; }
  else if (b < 4352) { src = sw1; dst = sw1t; R=HD; C=FD; }
  else               { src = sw2; dst = sw2t; R=FD; C=HD; }
  int tile = b & 255;
  int ctiles = C >> 8;                   // 16 (C=4096) or 4 (C=1024)
  int tr = tile / ctiles, tc = tile - tr*ctiles;
  int r0 = tr*64, c0 = tc*256;

  __shared__ _Float16 t[64][264];        // +8 halves pad
  #pragma unroll
  for (int it = 0; it < 8; ++it) {
    int idx = it*512 + tid;              // 4096 f32x4 chunks
    int row = idx >> 6, c4 = idx & 63;
    f32x4 v = *(const f32x4*)(src + (size_t)(r0+row)*C + c0 + c4*4);
    f16x4 h; h[0]=(_Float16)v[0]; h[1]=(_Float16)v[1]; h[2]=(_Float16)v[2]; h[3]=(_Float16)v[3];
    *(f16x4*)&t[row][c4*4] = h;
  }
  __syncthreads();
  #pragma unroll
  for (int it = 0; it < 4; ++it) {
    int idx = it*512 + tid;              // 2048 f16x8 chunks
    int d = idx >> 3, c8 = idx & 7;
    f16x8 h;
    #pragma unroll
    for (int j = 0; j < 8; ++j) h[j] = t[c8*8+j][d];
    *(f16x8*)(dst + (size_t)(c0+d)*R + r0 + c8*8) = h;
  }
}

// ---------------- 3) router logits, fp64 accumulation --------------------------
__global__ __launch_bounds__(256) void router_kernel(const float* __restrict__ x,
    const float* __restrict__ rw, double* __restrict__ logits)
{
  int w = threadIdx.x >> 6, lane = threadIdx.x & 63;
  int tok = blockIdx.x*4 + w;
  const float* xr = x + (size_t)tok * HD;
  double acc[8] = {0,0,0,0,0,0,0,0};
  #pragma unroll
  for (int it = 0; it < 4; ++it) {
    int h = it*256 + lane*4;
    f32x4 xv = *(const f32x4*)(xr + h);
    #pragma unroll
    for (int j = 0; j < 4; ++j) {
      const float* wr = rw + (size_t)(h+j)*NE;
      f32x4 w0 = *(const f32x4*)wr;
      f32x4 w1v = *(const f32x4*)(wr+4);
      double xd = (double)xv[j];
      acc[0] += xd*(double)w0[0];  acc[1] += xd*(double)w0[1];
      acc[2] += xd*(double)w0[2];  acc[3] += xd*(double)w0[3];
      acc[4] += xd*(double)w1v[0]; acc[5] += xd*(double)w1v[1];
      acc[6] += xd*(double)w1v[2]; acc[7] += xd*(double)w1v[3];
    }
  }
  #pragma unroll
  for (int d = 1; d < 64; d <<= 1) {
    #pragma unroll
    for (int e = 0; e < 8; ++e) acc[e] += __shfl_xor(acc[e], d, 64);
  }
  if (lane == 0) {
    double* lp = logits + (size_t)tok*NE;
    #pragma unroll
    for (int e = 0; e < 8; ++e) lp[e] = acc[e];
  }
}

// ---------------- 4) top-2 gating ---------------------------------------------
__device__ __forceinline__ int wave_incl_scan(int v, int lane) {
  #pragma unroll
  for (int d = 1; d < 64; d <<= 1) {
    int u = __shfl_up(v, d, 64);
    if (lane >= d) v += u;
  }
  return v;
}

__global__ __launch_bounds__(1024) void gating_kernel(const double* __restrict__ logits,
    int4* __restrict__ meta_i, f32x2* __restrict__ meta_f,
    int* __restrict__ slot_src, int* __restrict__ rows_dev)
{
  __shared__ unsigned char sE1[NTOK], sE2[NTOK];
  __shared__ float sG1[NTOK], sG2[NTOK];
  __shared__ int wsum1[8][16], wsum2[8][16];
  int tid = threadIdx.x, lane = tid & 63, w = tid >> 6;

  for (int i = tid; i < NSLOT; i += 1024) slot_src[i] = 0;

  int lc1[8] = {0,0,0,0,0,0,0,0}, lc2[8] = {0,0,0,0,0,0,0,0};
  #pragma unroll 1
  for (int i = 0; i < 4; ++i) {
    int n = tid*4 + i;
    const double* lp = logits + (size_t)n*NE;
    double l[8];
    #pragma unroll
    for (int e = 0; e < 8; ++e) l[e] = lp[e];
    int e1 = 0; double b1v = l[0];
    #pragma unroll
    for (int e = 1; e < 8; ++e) if (l[e] > b1v) { b1v = l[e]; e1 = e; }
    float s = 0.0f;
    #pragma unroll
    for (int e = 0; e < 8; ++e) s += __expf((float)(l[e] - b1v));
    int e2 = 0; double b2v = -1e300;
    #pragma unroll
    for (int e = 0; e < 8; ++e) if (e != e1 && l[e] > b2v) { b2v = l[e]; e2 = e; }
    sE1[n] = (unsigned char)e1; sE2[n] = (unsigned char)e2;
    sG1[n] = 1.0f / s;
    sG2[n] = __expf((float)(b2v - b1v)) / s;
    #pragma unroll
    for (int e = 0; e < 8; ++e) { lc1[e] += (e==e1); lc2[e] += (e==e2); }
  }
  int inc1[8], inc2[8];
  #pragma unroll
  for (int e = 0; e < 8; ++e) {
    inc1[e] = wave_incl_scan(lc1[e], lane);
    inc2[e] = wave_incl_scan(lc2[e], lane);
    if (lane == 63) { wsum1[e][w] = inc1[e]; wsum2[e][w] = inc2[e]; }
  }
  __syncthreads();
  int off1[8], off2[8], tot2[8], kept1[8];
  #pragma unroll
  for (int e = 0; e < 8; ++e) {
    int wp1=0, wp2=0, t1=0, t2=0;
    #pragma unroll
    for (int j = 0; j < 16; ++j) {
      int v1 = wsum1[e][j], v2 = wsum2[e][j];
      if (j < w) { wp1 += v1; wp2 += v2; }
      t1 += v1; t2 += v2;
    }
    off1[e] = inc1[e] - lc1[e] + wp1;
    off2[e] = inc2[e] - lc2[e] + wp2;
    tot2[e] = t2;
    kept1[e] = min(t1, CAP);
  }
  int r1[8], r2[8];
  #pragma unroll
  for (int e = 0; e < 8; ++e) { r1[e] = off1[e]; r2[e] = off2[e]; }
  #pragma unroll 1
  for (int i = 0; i < 4; ++i) {
    int n = tid*4 + i;
    int e1 = sE1[n], e2 = sE2[n];
    int p1 = 0, p2 = 0, k1off = 0;
    #pragma unroll
    for (int e = 0; e < 8; ++e) {
      if (e == e1) { p1 = r1[e]; r1[e] = p1 + 1; }
      if (e == e2) { p2 = r2[e]; r2[e] = p2 + 1; k1off = kept1[e]; }
    }
    int loc1 = (p1 < CAP) ? p1 : -1;
    int pp2 = p2 + k1off;
    int loc2 = (pp2 < CAP) ? pp2 : -1;
    float gg1 = (loc1 >= 0) ? sG1[n] : 0.0f;
    float gg2 = (loc2 >= 0) ? sG2[n] : 0.0f;
    float denom = fmaxf(gg1 + gg2, 1.1920929e-07f);
    meta_i[n] = make_int4(e1, loc1, e2, loc2);
    f32x2 mf; mf[0] = gg1/denom; mf[1] = gg2/denom;
    meta_f[n] = mf;
    if (loc1 >= 0) slot_src[e1*CAP + loc1] = n;
    if (loc2 >= 0) slot_src[e2*CAP + loc2] = n;
  }
  if (tid < 8) {
    int rr = 0;
    #pragma unroll
    for (int e = 0; e < 8; ++e) if (e == tid) rr = min(kept1[e] + tot2[e], CAP);
    rows_dev[tid] = rr;
  }
}

// ---------------- 5/6) grouped GEMM: 256x256 tile, BK=64, 8 waves, phase-pipelined
// Template per guide §5 (m201). Register budget via direct LLVM attributes:
// amdgpu_waves_per_eu(2,2) pins occupancy target to 2 waves/EU -> 256 VGPR cap.
// (Round-1's __launch_bounds__(512,2) was silently ignored: VGPR stayed 128 and
// ~90 regs spilled -> 309MB scratch writes/dispatch. LDS 128KB caps occupancy at
// 1 block/CU = 2 waves/EU regardless, so this costs no occupancy.)
//
// Per-phase slot-liveness invariants (race-freedom):
//   A-slots[pt] last ds_read at p1 (lgkmcnt(0) before p1 barrier) -> restaged p2 (t+2)
//   B-slots[pt] last ds_read at p2 -> restaged p3 (t+2)
//   B-slot[1-pt][1] last read during K-tile t-1 p2 -> restaged p0 (B1 of t+1)
//   boundary vmcnt(6): loads issued after B1(t+1) = 4 (A t+2) + 2 (B0 t+2) = 6.
template<int V> struct IC { static constexpr int value = V; };

template<int K, int NOUT, bool G1>
__global__
__attribute__((amdgpu_flat_work_group_size(512, 512), amdgpu_waves_per_eu(2, 2)))
void gemm_kernel(
    const _Float16* __restrict__ A0,     // x16 (G1) or mid16 (G2), row stride K
    const _Float16* __restrict__ Wexp,   // [E][NOUT][K] transposed weights
    const _Float16* __restrict__ Wshd,   // [NOUT][K]
    const float* __restrict__ BiasE,     // [E][NOUT]
    const float* __restrict__ BiasS,     // [NOUT]
    _Float16* __restrict__ Out,          // [TOTSLOT][NOUT]
    const int* __restrict__ slot_src,
    const int* __restrict__ rows_dev)
{
  constexpr int NXT = NOUT / 256;        // 16 (gemm1) / 4 (gemm2)
  constexpr int NRT = 56;                // 8 experts * 5 + 16 shared row-tiles
  constexpr int NWG = NRT * NXT;         // 896 / 224 (both % 8 == 0)
  constexpr int NT  = K / 64;            // 16 / 64 K-tiles
  static_assert((NT & 1) == 0, "NT must be even");

  extern __shared__ _Float16 smem[];
  _Float16* smA = smem;                  // [2 parity][2 half][128*64] f16 = 64KB
  _Float16* smB = smem + 32768;          // same, 64KB

  int bid = blockIdx.x;
  // XCD-bijective chunked swizzle (rt-major): each XCD owns NWG/8 consecutive wgs
  int wg = (bid & 7) * (NWG / 8) + (bid >> 3);
  int rt = wg / NXT, nt = wg % NXT;
  int n0 = nt * 256;
  int g, tile;
  if (rt < 40) { g = rt / 5; tile = rt - g*5; } else { g = 8; tile = rt - 40; }
  int rows = (g < 8) ? rows_dev[g] : NTOK;
  if (tile * 256 >= rows) return;        // uniform whole-block exit, before barriers
  int slot_base = (g < 8) ? g * CAP : NSLOT;
  const _Float16* Bw = (g < 8) ? (Wexp + (size_t)g * NOUT * K) : Wshd;
  const float* bias = (g < 8) ? (BiasE + g * NOUT) : BiasS;

  int tid = threadIdx.x, lane = tid & 63, w = tid >> 6;   // 8 waves
  int wm = w & 1, wn = w >> 1;           // wave tile: rows [wm*128,+128) cols [wn*64,+64)

  // --- staging source offsets (pre-swizzled global so LDS stays linear, rule 21)
  // thread stages LDS slot (lane&7) of row c*64 + w*8 + (lane>>3) in half h;
  // that slot holds global 16B chunk  slot ^ (row&7)  (row&7 == (lane>>3)&7)
  int gch = ((lane & 7) ^ ((lane >> 3) & 7)) * 8;   // f16 offset of global chunk
  unsigned aoff[2][2], boff[2][2];       // [half][call] row-base offsets (f16 units)
  #pragma unroll
  for (int h = 0; h < 2; ++h)
    #pragma unroll
    for (int c = 0; c < 2; ++c) {
      int r = h*128 + c*64 + w*8 + (lane >> 3);
      int rg = tile*256 + r;
      unsigned arow;
      if (G1) arow = (g < 8) ? (unsigned)slot_src[g*CAP + rg] : (unsigned)rg;
      else    arow = (unsigned)(slot_base + rg);
      aoff[h][c] = arow * (unsigned)K + (unsigned)gch;
      boff[h][c] = (unsigned)(n0 + r) * (unsigned)K + (unsigned)gch;
    }

#define STG_A(PT_, H_, C_, TT_) load_lds16(A0 + aoff[H_][C_] + (unsigned)((TT_)*64), \
                                 smA + ((PT_)*2+(H_))*8192 + (C_)*4096 + w*512)
#define STG_B(PT_, H_, C_, TT_) load_lds16(Bw + boff[H_][C_] + (unsigned)((TT_)*64), \
                                 smB + ((PT_)*2+(H_))*8192 + (C_)*4096 + w*512)

  // --- fragment read bases. 16x16x32 frag: lane holds op[row=l&15][k=(l>>4)*8 +j],
  // read 16B at swizzled slot ((ks*4 + (l>>4)) ^ (row&7)); row&7 == lane&7 (16|rows)
  int c0o = (((lane >> 4)    ) ^ (lane & 7)) * 8;
  int c1o = ((4 + (lane >> 4)) ^ (lane & 7)) * 8;
  const _Float16* Ab0 = smA + wm*8192 + (lane & 15)*64;          // parity 0
  const _Float16* Ab1 = Ab0 + 16384;                             // parity 1
  const _Float16* Bb0 = smB + (wn >> 1)*8192 + (wn & 1)*4096 + (lane & 15)*64;
  const _Float16* Bb1 = Bb0 + 16384;

  f32x4 acc[8][4];
  #pragma unroll
  for (int i = 0; i < 8; ++i)
    #pragma unroll
    for (int j = 0; j < 4; ++j) acc[i][j] = (f32x4)0.0f;

  f16x8 af0[8], af1[8], bf[4];

  // --- prologue: K0 fully + K1's A0,A1,B0 (B1(1) staged at t=0 p0). vmcnt(6): K0 in.
  STG_A(0,0,0,0); STG_A(0,0,1,0); STG_A(0,1,0,0); STG_A(0,1,1,0);
  STG_B(0,0,0,0); STG_B(0,0,1,0); STG_B(0,1,0,0); STG_B(0,1,1,0);
  STG_A(1,0,0,1); STG_A(1,0,1,1); STG_A(1,1,0,1); STG_A(1,1,1,1);
  STG_B(1,0,0,1); STG_B(1,0,1,1);
  asm volatile("s_waitcnt vmcnt(6)\ns_barrier" ::: "memory");

  auto ktile = [&](int T, auto pc) {
    constexpr int PT = decltype(pc)::value;
    const _Float16* Ab = PT ? Ab1 : Ab0;
    const _Float16* Bb = PT ? Bb1 : Bb0;
    // ---- p0: read A ks0 (8) + B ks0 (4); stage B1(t+1); MFMA ks0 x m0-3
    #pragma unroll
    for (int mi = 0; mi < 8; ++mi) af0[mi] = *(const f16x8*)(Ab + mi*1024 + c0o);
    #pragma unroll
    for (int ni = 0; ni < 4; ++ni) bf[ni]  = *(const f16x8*)(Bb + ni*1024 + c0o);
    if (T + 1 < NT) { STG_B(1-PT, 1, 0, T+1); STG_B(1-PT, 1, 1, T+1); }
    asm volatile("s_waitcnt lgkmcnt(0)\ns_barrier" ::: "memory");
    __builtin_amdgcn_s_setprio(1);
    #pragma unroll
    for (int mi = 0; mi < 4; ++mi)
      #pragma unroll
      for (int ni = 0; ni < 4; ++ni)
        acc[mi][ni] = __builtin_amdgcn_mfma_f32_16x16x32_f16(af0[mi], bf[ni], acc[mi][ni], 0, 0, 0);
    __builtin_amdgcn_s_setprio(0);
    // ---- p1: read A ks1 (8); MFMA ks0 x m4-7
    #pragma unroll
    for (int mi = 0; mi < 8; ++mi) af1[mi] = *(const f16x8*)(Ab + mi*1024 + c1o);
    asm volatile("s_waitcnt lgkmcnt(0)\ns_barrier" ::: "memory");
    __builtin_amdgcn_s_setprio(1);
    #pragma unroll
    for (int mi = 0; mi < 4; ++mi)
      #pragma unroll
      for (int ni = 0; ni < 4; ++ni)
        acc[4+mi][ni] = __builtin_amdgcn_mfma_f32_16x16x32_f16(af0[4+mi], bf[ni], acc[4+mi][ni], 0, 0, 0);
    __builtin_amdgcn_s_setprio(0);
    // ---- p2: read B ks1 (4); stage A0,A1(t+2) (A-slots free after p1); MFMA ks1 x m0-3
    #pragma unroll
    for (int ni = 0; ni < 4; ++ni) bf[ni] = *(const f16x8*)(Bb + ni*1024 + c1o);
    if (T + 2 < NT) { STG_A(PT, 0, 0, T+2); STG_A(PT, 0, 1, T+2);
                      STG_A(PT, 1, 0, T+2); STG_A(PT, 1, 1, T+2); }
    asm volatile("s_waitcnt lgkmcnt(0)\ns_barrier" ::: "memory");
    __builtin_amdgcn_s_setprio(1);
    #pragma unroll
    for (int mi = 0; mi < 4; ++mi)
      #pragma unroll
      for (int ni = 0; ni < 4; ++ni)
        acc[mi][ni] = __builtin_amdgcn_mfma_f32_16x16x32_f16(af1[mi], bf[ni], acc[mi][ni], 0, 0, 0);
    __builtin_amdgcn_s_setprio(0);
    // ---- p3: stage B0(t+2) (B-slots free after p2); K-tile boundary wait; MFMA ks1 x m4-7
    if (T + 2 < NT) { STG_B(PT, 0, 0, T+2); STG_B(PT, 0, 1, T+2); }
    if (T + 2 < NT)      asm volatile("s_waitcnt vmcnt(6) lgkmcnt(0)\ns_barrier" ::: "memory");
    else if (T + 1 < NT) asm volatile("s_waitcnt vmcnt(0) lgkmcnt(0)\ns_barrier" ::: "memory");
    else                 asm volatile("s_waitcnt lgkmcnt(0)\ns_barrier" ::: "memory");
    __builtin_amdgcn_s_setprio(1);
    #pragma unroll
    for (int mi = 0; mi < 4; ++mi)
      #pragma unroll
      for (int ni = 0; ni < 4; ++ni)
        acc[4+mi][ni] = __builtin_amdgcn_mfma_f32_16x16x32_f16(af1[4+mi], bf[ni], acc[4+mi][ni], 0, 0, 0);
    __builtin_amdgcn_s_setprio(0);
  };

  for (int t = 0; t < NT; t += 2) {
    ktile(t,   IC<0>{});
    ktile(t+1, IC<1>{});
  }
#undef STG_A
#undef STG_B

  // --- epilogue. 16x16 C/D: col = lane&15, row = (lane>>4)*4 + reg  (m89/m91)
  float bias_v[4];
  #pragma unroll
  for (int ni = 0; ni < 4; ++ni) bias_v[ni] = bias[n0 + wn*64 + ni*16 + (lane & 15)];
  #pragma unroll
  for (int mi = 0; mi < 8; ++mi) {
    #pragma unroll
    for (int reg = 0; reg < 4; ++reg) {
      int m = wm*128 + mi*16 + (lane >> 4)*4 + reg;
      int rg = tile*256 + m;
      if (rg < rows) {
        size_t orow = (size_t)(slot_base + rg);
        #pragma unroll
        for (int ni = 0; ni < 4; ++ni) {
          int n = n0 + wn*64 + ni*16 + (lane & 15);
          float v = acc[mi][ni][reg] + bias_v[ni];
          if (G1) v = v / (1.0f + __expf(-v));   // SiLU
          Out[orow * (size_t)NOUT + n] = (_Float16)v;
        }
      }
    }
  }
}

// ---------------- 7) combine: y = g1*e1out + g2*e2out + 0.1*shared -------------
__global__ __launch_bounds__(256) void combine_kernel(const int4* __restrict__ meta_i,
    const f32x2* __restrict__ meta_f, const _Float16* __restrict__ out16,
    float* __restrict__ out)
{
  int n = blockIdx.x;
  int h = threadIdx.x * 4;
  int4 mi = meta_i[n];
  f32x2 mf = meta_f[n];
  f16x4 sv = *(const f16x4*)(out16 + (size_t)(NSLOT + n)*HD + h);
  f32x4 y;
  #pragma unroll
  for (int j = 0; j < 4; ++j) y[j] = 0.1f * (float)sv[j];
  if (mi.y >= 0) {
    f16x4 v = *(const f16x4*)(out16 + (size_t)(mi.x*CAP + mi.y)*HD + h);
    #pragma unroll
    for (int j = 0; j < 4; ++j) y[j] += mf[0] * (float)v[j];
  }
  if (mi.w >= 0) {
    f16x4 v = *(const f16x4*)(out16 + (size_t)(mi.z*CAP + mi.w)*HD + h);
    #pragma unroll
    for (int j = 0; j < 4; ++j) y[j] += mf[1] * (float)v[j];
  }
  *(f32x4*)(out + (size_t)n*HD + h) = y;
}

__global__ void fill_sentinel(float* out, int nelem) {
  int i = blockIdx.x*256 + threadIdx.x;
  if (i < nelem) out[i] = 12345.0f;
}

// ---------------- host ----------------
extern "C" void kernel_launch(void* const* d_in, const int* in_sizes, int n_in,
                              void* d_out, int out_size, void* d_ws, size_t ws_size,
                              hipStream_t stream) {
  const float* x   = (const float*)d_in[0];
  const float* rw  = (const float*)d_in[1];
  const float* w1  = (const float*)d_in[2];
  const float* b1  = (const float*)d_in[3];
  const float* w2  = (const float*)d_in[4];
  const float* b2  = (const float*)d_in[5];
  const float* sw1 = (const float*)d_in[6];
  const float* sb1 = (const float*)d_in[7];
  const float* sw2 = (const float*)d_in[8];
  const float* sb2 = (const float*)d_in[9];
  float* out = (float*)d_out;

  char* p = (char*)d_ws;
  auto alloc = [&](size_t bytes) { char* r = p; p += (bytes + 255) & ~(size_t)255; return r; };
  _Float16* x16  = (_Float16*)alloc((size_t)NTOK*HD*2);
  _Float16* w1t  = (_Float16*)alloc((size_t)NE*FD*HD*2);
  _Float16* w2t  = (_Float16*)alloc((size_t)NE*HD*FD*2);
  _Float16* sw1t = (_Float16*)alloc((size_t)FD*HD*2);
  _Float16* sw2t = (_Float16*)alloc((size_t)HD*FD*2);
  _Float16* mid  = (_Float16*)alloc((size_t)TOTSLOT*FD*2);
  _Float16* o16  = (_Float16*)alloc((size_t)TOTSLOT*HD*2);
  double* logits = (double*)alloc((size_t)NTOK*NE*8);
  int4*   meta_i = (int4*)alloc((size_t)NTOK*16);
  f32x2*  meta_f = (f32x2*)alloc((size_t)NTOK*8);
  int* slot_src  = (int*)alloc((size_t)NSLOT*4);
  int* rows_dev  = (int*)alloc(64);
  size_t need = (size_t)(p - (char*)d_ws);
  if (need > ws_size) {
    fill_sentinel<<<(out_size+255)/256, 256, 0, stream>>>(out, out_size);
    return;
  }

  transpose_cvt<<<4864, 512, 0, stream>>>(w1, w2, sw1, sw2, x, w1t, w2t, sw1t, sw2t, x16);
  router_kernel<<<NTOK/4, 256, 0, stream>>>(x, rw, logits);
  gating_kernel<<<1, 1024, 0, stream>>>(logits, meta_i, meta_f, slot_src, rows_dev);
  // 256^2 tiles: 56 row-tiles (8 experts x 5 + 16 shared) x NOUT/256 n-tiles
  gemm_kernel<HD, FD, true><<<56*(FD/256), 512, 131072, stream>>>(
      x16, w1t, sw1t, b1, sb1, mid, slot_src, rows_dev);
  gemm_kernel<FD, HD, false><<<56*(HD/256), 512, 131072, stream>>>(
      mid, w2t, sw2t, b2, sb2, o16, slot_src, rows_dev);
  combine_kernel<<<NTOK, 256, 0, stream>>>(meta_i, meta_f, o16, out);
}

// Round 4
// 752.292 us; speedup vs baseline: 1.4564x; 1.4564x over previous
//
#include <hip/hip_runtime.h>
#include <cstdint>
#include <cstddef>

// ---------------- problem constants ----------------
#define HD    1024
#define FD    4096
#define NE    8
#define NTOK  4096            // 2*2048
#define CAP   1280            // ceil(2*1.25*4096/8)
#define NSLOT (NE*CAP)        // 10240 expert slots
#define TOTSLOT (NSLOT+NTOK)  // + shared rows

typedef float    f32x4  __attribute__((ext_vector_type(4)));
typedef float    f32x2  __attribute__((ext_vector_type(2)));
typedef float    f32x16 __attribute__((ext_vector_type(16)));
typedef _Float16 f16x8  __attribute__((ext_vector_type(8)));
typedef _Float16 f16x4  __attribute__((ext_vector_type(4)));

typedef __attribute__((address_space(3))) unsigned int as3_u32;
typedef __attribute__((address_space(1))) unsigned int as1_u32;

__device__ __forceinline__ void load_lds16(const _Float16* g, _Float16* l) {
  __builtin_amdgcn_global_load_lds((const as1_u32*)g, (as3_u32*)l, 16, 0, 0);
}

// ---------------- 1) weight convert+transpose + x convert ----------------------
// 64(src rows) x 256(src cols) tiles: 1KB contiguous read per row visit,
// fp16 in LDS (33KB), f16x8 writes. Blocks 0..4607 = transpose, 4608..4863 = x cvt.
__global__ __launch_bounds__(512) void transpose_cvt(
    const float* __restrict__ w1, const float* __restrict__ w2,
    const float* __restrict__ sw1, const float* __restrict__ sw2,
    const float* __restrict__ x,
    _Float16* __restrict__ w1t, _Float16* __restrict__ w2t,
    _Float16* __restrict__ sw1t, _Float16* __restrict__ sw2t,
    _Float16* __restrict__ x16)
{
  int b = blockIdx.x;
  int tid = threadIdx.x;
  if (b >= 4608) {                       // x: 4096*1024 f32 -> f16, 256 blocks
    int cb = b - 4608;
    #pragma unroll
    for (int it = 0; it < 8; ++it) {
      size_t i = (size_t)cb*16384 + (size_t)(it*512 + tid)*4;
      f32x4 v = *(const f32x4*)(x + i);
      f16x4 h; h[0]=(_Float16)v[0]; h[1]=(_Float16)v[1]; h[2]=(_Float16)v[2]; h[3]=(_Float16)v[3];
      *(f16x4*)(x16 + i) = h;
    }
    return;
  }
  const float* src; _Float16* dst; int R, C;
  if (b < 2048)      { int e = b>>8;        src = w1 + (size_t)e*HD*FD; dst = w1t + (size_t)e*FD*HD; R=HD; C=FD; }
  else if (b < 4096) { int e = (b-2048)>>8; src = w2 + (size_t)e*FD*HD; dst = w2t + (size_t)e*HD*FD; R=FD; C=HD; }
  else if (b < 4352) { src = sw1; dst = sw1t; R=HD; C=FD; }
  else               { src = sw2; dst = sw2t; R=FD; C=HD; }
  int tile = b & 255;
  int ctiles = C >> 8;                   // 16 (C=4096) or 4 (C=1024)
  int tr = tile / ctiles, tc = tile - tr*ctiles;
  int r0 = tr*64, c0 = tc*256;

  __shared__ _Float16 t[64][264];        // +8 halves pad: keeps 16B align, breaks conflicts
  #pragma unroll
  for (int it = 0; it < 8; ++it) {
    int idx = it*512 + tid;              // 4096 f32x4 chunks
    int row = idx >> 6, c4 = idx & 63;
    f32x4 v = *(const f32x4*)(src + (size_t)(r0+row)*C + c0 + c4*4);
    f16x4 h; h[0]=(_Float16)v[0]; h[1]=(_Float16)v[1]; h[2]=(_Float16)v[2]; h[3]=(_Float16)v[3];
    *(f16x4*)&t[row][c4*4] = h;
  }
  __syncthreads();
  #pragma unroll
  for (int it = 0; it < 4; ++it) {
    int idx = it*512 + tid;              // 2048 f16x8 chunks
    int d = idx >> 3, c8 = idx & 7;      // d = dst row (src col), c8*8 = dst col chunk
    f16x8 h;
    #pragma unroll
    for (int j = 0; j < 8; ++j) h[j] = t[c8*8+j][d];
    *(f16x8*)(dst + (size_t)(c0+d)*R + r0 + c8*8) = h;
  }
}

// ---------------- 3) router logits, fp64 accumulation (tie-flip insurance) -----
__global__ __launch_bounds__(256) void router_kernel(const float* __restrict__ x,
    const float* __restrict__ rw, double* __restrict__ logits)
{
  int w = threadIdx.x >> 6, lane = threadIdx.x & 63;
  int tok = blockIdx.x*4 + w;
  const float* xr = x + (size_t)tok * HD;
  double acc[8] = {0,0,0,0,0,0,0,0};
  #pragma unroll
  for (int it = 0; it < 4; ++it) {
    int h = it*256 + lane*4;
    f32x4 xv = *(const f32x4*)(xr + h);
    #pragma unroll
    for (int j = 0; j < 4; ++j) {
      const float* wr = rw + (size_t)(h+j)*NE;
      f32x4 w0 = *(const f32x4*)wr;
      f32x4 w1v = *(const f32x4*)(wr+4);
      double xd = (double)xv[j];
      acc[0] += xd*(double)w0[0];  acc[1] += xd*(double)w0[1];
      acc[2] += xd*(double)w0[2];  acc[3] += xd*(double)w0[3];
      acc[4] += xd*(double)w1v[0]; acc[5] += xd*(double)w1v[1];
      acc[6] += xd*(double)w1v[2]; acc[7] += xd*(double)w1v[3];
    }
  }
  #pragma unroll
  for (int d = 1; d < 64; d <<= 1) {
    #pragma unroll
    for (int e = 0; e < 8; ++e) acc[e] += __shfl_xor(acc[e], d, 64);
  }
  if (lane == 0) {
    double* lp = logits + (size_t)tok*NE;
    #pragma unroll
    for (int e = 0; e < 8; ++e) lp[e] = acc[e];
  }
}

// ---------------- 4) top-2 gating: 1024 threads, float expf --------------------
__device__ __forceinline__ int wave_incl_scan(int v, int lane) {
  #pragma unroll
  for (int d = 1; d < 64; d <<= 1) {
    int u = __shfl_up(v, d, 64);
    if (lane >= d) v += u;
  }
  return v;
}

__global__ __launch_bounds__(1024) void gating_kernel(const double* __restrict__ logits,
    int4* __restrict__ meta_i, f32x2* __restrict__ meta_f,
    int* __restrict__ slot_src, int* __restrict__ rows_dev)
{
  __shared__ unsigned char sE1[NTOK], sE2[NTOK];
  __shared__ float sG1[NTOK], sG2[NTOK];
  __shared__ int wsum1[8][16], wsum2[8][16];
  int tid = threadIdx.x, lane = tid & 63, w = tid >> 6;

  for (int i = tid; i < NSLOT; i += 1024) slot_src[i] = 0;  // unused slots -> token 0

  int lc1[8] = {0,0,0,0,0,0,0,0}, lc2[8] = {0,0,0,0,0,0,0,0};
  #pragma unroll 1
  for (int i = 0; i < 4; ++i) {
    int n = tid*4 + i;
    const double* lp = logits + (size_t)n*NE;
    double l[8];
    #pragma unroll
    for (int e = 0; e < 8; ++e) l[e] = lp[e];
    int e1 = 0; double b1v = l[0];
    #pragma unroll
    for (int e = 1; e < 8; ++e) if (l[e] > b1v) { b1v = l[e]; e1 = e; }  // first-occurrence argmax
    float s = 0.0f;
    #pragma unroll
    for (int e = 0; e < 8; ++e) s += __expf((float)(l[e] - b1v));
    int e2 = 0; double b2v = -1e300;
    #pragma unroll
    for (int e = 0; e < 8; ++e) if (e != e1 && l[e] > b2v) { b2v = l[e]; e2 = e; }
    sE1[n] = (unsigned char)e1; sE2[n] = (unsigned char)e2;
    sG1[n] = 1.0f / s;
    sG2[n] = __expf((float)(b2v - b1v)) / s;
    #pragma unroll
    for (int e = 0; e < 8; ++e) { lc1[e] += (e==e1); lc2[e] += (e==e2); }
  }
  int inc1[8], inc2[8];
  #pragma unroll
  for (int e = 0; e < 8; ++e) {
    inc1[e] = wave_incl_scan(lc1[e], lane);
    inc2[e] = wave_incl_scan(lc2[e], lane);
    if (lane == 63) { wsum1[e][w] = inc1[e]; wsum2[e][w] = inc2[e]; }
  }
  __syncthreads();
  int off1[8], off2[8], tot2[8], kept1[8];
  #pragma unroll
  for (int e = 0; e < 8; ++e) {
    int wp1=0, wp2=0, t1=0, t2=0;
    #pragma unroll
    for (int j = 0; j < 16; ++j) {
      int v1 = wsum1[e][j], v2 = wsum2[e][j];
      if (j < w) { wp1 += v1; wp2 += v2; }
      t1 += v1; t2 += v2;
    }
    off1[e] = inc1[e] - lc1[e] + wp1;
    off2[e] = inc2[e] - lc2[e] + wp2;
    tot2[e] = t2;
    kept1[e] = min(t1, CAP);          // = sum(mask1) after capacity drop
  }
  int r1[8], r2[8];
  #pragma unroll
  for (int e = 0; e < 8; ++e) { r1[e] = off1[e]; r2[e] = off2[e]; }
  #pragma unroll 1
  for (int i = 0; i < 4; ++i) {
    int n = tid*4 + i;
    int e1 = sE1[n], e2 = sE2[n];
    int p1 = 0, p2 = 0, k1off = 0;
    #pragma unroll
    for (int e = 0; e < 8; ++e) {
      if (e == e1) { p1 = r1[e]; r1[e] = p1 + 1; }
      if (e == e2) { p2 = r2[e]; r2[e] = p2 + 1; k1off = kept1[e]; }
    }
    int loc1 = (p1 < CAP) ? p1 : -1;
    int pp2 = p2 + k1off;
    int loc2 = (pp2 < CAP) ? pp2 : -1;
    float gg1 = (loc1 >= 0) ? sG1[n] : 0.0f;
    float gg2 = (loc2 >= 0) ? sG2[n] : 0.0f;
    float denom = fmaxf(gg1 + gg2, 1.1920929e-07f);  // finfo(f32).eps
    meta_i[n] = make_int4(e1, loc1, e2, loc2);
    f32x2 mf; mf[0] = gg1/denom; mf[1] = gg2/denom;
    meta_f[n] = mf;
    if (loc1 >= 0) slot_src[e1*CAP + loc1] = n;
    if (loc2 >= 0) slot_src[e2*CAP + loc2] = n;
  }
  if (tid < 8) {
    int rr = 0;
    #pragma unroll
    for (int e = 0; e < 8; ++e) if (e == tid) rr = min(kept1[e] + tot2[e], CAP);
    rows_dev[tid] = rr;     // occupied slots are contiguous [0, rows)
  }
}

// ---------------- 5/6) grouped GEMM: 32x32x16 MFMA + per-GEMM XCD mapping ------
// 128x128 tile, BK=64, 4 waves (2x2), each wave 2x2 tiles of 32x32x16 f16 MFMA.
// ROUND-4 DELTA (only change vs the 713us round-0 kernel): double-buffered LDS
// (32->64KB, still 2 blocks/CU) + prefetch loop. Old loop was
// stage->__syncthreads(full vmcnt drain)->compute->__syncthreads: every K-step
// exposed the full global_load_lds latency (MfmaUtil 21.6%, latency-bound).
// New loop (catalog T3-minimum, m230/m248): issue STAGE(buf^1, t+1) FIRST, then
// compute buf[t], then ONE raw "s_waitcnt vmcnt(0) lgkmcnt(0); s_barrier".
// Next-tile loads land under the current tile's 16 MFMAs. Race-free: a wave
// passing the iter-t barrier has drained its ds_reads (lgkmcnt 0), so iter-t+1's
// overwrite of buf^1 is safe; raw asm barrier avoids the compiler's pre-barrier
// vmcnt drain (the m97-ceiling mechanism).
template<int K, int NOUT, bool G1>
__global__ __launch_bounds__(256) void gemm_kernel(
    const _Float16* __restrict__ A0,     // x16 (G1) or mid16 (G2), row stride K
    const _Float16* __restrict__ Wexp,   // [E][NOUT][K] transposed weights
    const _Float16* __restrict__ Wshd,   // [NOUT][K]
    const float* __restrict__ BiasE,     // [E][NOUT]
    const float* __restrict__ BiasS,     // [NOUT]
    _Float16* __restrict__ Out,          // [TOTSLOT][NOUT]
    const int* __restrict__ slot_src,
    const int* __restrict__ rows_dev)
{
  constexpr int NXT = NOUT / 128;        // n-tiles: 32 (gemm1) / 8 (gemm2)
  int bid = blockIdx.x;
  int rt, nt;
  if (G1) {                              // n-fastest, natural round-robin
    nt = bid & (NXT - 1); rt = bid >> 5; // NXT==32
  } else {                               // co-located row-tiles per XCD
    int idx = (bid & 7) * (14 * NXT) + (bid >> 3);
    rt = idx / NXT; nt = idx - rt * NXT;
  }
  int n0 = nt * 128;

  int g, tile;
  if (rt < 80) { g = rt / 10; tile = rt % 10; } else { g = 8; tile = rt - 80; }
  int rows = (g < 8) ? rows_dev[g] : NTOK;
  if (tile * 128 >= rows) return;
  int slot_base = (g < 8) ? g * CAP : NSLOT;
  const _Float16* Bw = (g < 8) ? (Wexp + (size_t)g * NOUT * K) : Wshd;
  const float* bias = (g < 8) ? (BiasE + g * NOUT) : BiasS;

  __shared__ _Float16 Ash[2][128*64];    // double-buffered: 64KB total
  __shared__ _Float16 Bsh[2][128*64];

  int tid = threadIdx.x, lane = tid & 63, w = tid >> 6;
  int wm = w & 1, wn = w >> 1;

  // staging: slot s = lane&7 of row-group fetches global chunk kc = s ^ (r&7)
  int kc = ((lane & 7) ^ ((lane >> 3) & 7)) * 8;
  const _Float16* aptr[4];
  const _Float16* bptr[4];
  #pragma unroll
  for (int i = 0; i < 4; ++i) {
    int r = (w*4 + i)*8 + (lane >> 3);
    int rg = tile*128 + r;
    size_t arow;
    if (G1) arow = (g < 8) ? (size_t)slot_src[g*CAP + rg] : (size_t)rg;
    else    arow = (size_t)(slot_base + rg);
    aptr[i] = A0 + arow * (size_t)K + kc;
    bptr[i] = Bw + (size_t)(n0 + r) * K + kc;
  }

  f32x16 acc[2][2];
  #pragma unroll
  for (int mi = 0; mi < 2; ++mi)
    #pragma unroll
    for (int ni = 0; ni < 2; ++ni)
      acc[mi][ni] = (f32x16)0.0f;

  constexpr int NSTEP = K / 64;
  // prologue: stage tile 0 into buf 0
  #pragma unroll
  for (int i = 0; i < 4; ++i) load_lds16(aptr[i], &Ash[0][(w*4+i)*512]);
  #pragma unroll
  for (int i = 0; i < 4; ++i) load_lds16(bptr[i], &Bsh[0][(w*4+i)*512]);
  asm volatile("s_waitcnt vmcnt(0)\ns_barrier" ::: "memory");

  #pragma unroll 1
  for (int t = 0; t < NSTEP; ++t) {
    int cur = t & 1;
    const _Float16* Ac = &Ash[cur][0];
    const _Float16* Bc = &Bsh[cur][0];
    _Float16* An = &Ash[cur ^ 1][0];
    _Float16* Bn = &Bsh[cur ^ 1][0];
    if (t + 1 < NSTEP) {                       // issue next-tile loads FIRST
      int k0 = (t + 1) * 64;
      #pragma unroll
      for (int i = 0; i < 4; ++i) load_lds16(aptr[i] + k0, An + (w*4+i)*512);
      #pragma unroll
      for (int i = 0; i < 4; ++i) load_lds16(bptr[i] + k0, Bn + (w*4+i)*512);
    }
    #pragma unroll
    for (int ks = 0; ks < 4; ++ks) {           // k = 16 per step
      int chunk = ks*2 + (lane >> 5);          // 16B chunk holding this lane's 8 k-vals
      f16x8 af[2], bf[2];
      #pragma unroll
      for (int mi = 0; mi < 2; ++mi) {
        int row = wm*64 + mi*32 + (lane & 31);
        af[mi] = *(const f16x8*)&Ac[row*64 + (chunk ^ (row & 7))*8];
      }
      #pragma unroll
      for (int ni = 0; ni < 2; ++ni) {
        int row = wn*64 + ni*32 + (lane & 31);
        bf[ni] = *(const f16x8*)&Bc[row*64 + (chunk ^ (row & 7))*8];
      }
      #pragma unroll
      for (int mi = 0; mi < 2; ++mi)
        #pragma unroll
        for (int ni = 0; ni < 2; ++ni)
          acc[mi][ni] = __builtin_amdgcn_mfma_f32_32x32x16_f16(af[mi], bf[ni], acc[mi][ni], 0, 0, 0);
    }
    // ONE barrier per K-step: waits for next-tile loads (had whole compute to land)
    // + own ds_reads; then buffers swap.
    asm volatile("s_waitcnt vmcnt(0) lgkmcnt(0)\ns_barrier" ::: "memory");
  }

  // epilogue: 32x32 C/D layout col=lane&31, row=(reg&3)+8*(reg>>2)+4*(lane>>5)  (m74/m101)
  #pragma unroll
  for (int mi = 0; mi < 2; ++mi) {
    #pragma unroll
    for (int reg = 0; reg < 16; ++reg) {
      int m = wm*64 + mi*32 + (reg & 3) + 8*(reg >> 2) + 4*(lane >> 5);
      int rg = tile*128 + m;
      if (rg < rows) {
        size_t orow = (size_t)(slot_base + rg);
        #pragma unroll
        for (int ni = 0; ni < 2; ++ni) {
          int n = n0 + wn*64 + ni*32 + (lane & 31);
          float v = acc[mi][ni][reg] + bias[n];
          if (G1) v = v / (1.0f + __expf(-v));   // SiLU
          Out[orow * (size_t)NOUT + n] = (_Float16)v;
        }
      }
    }
  }
}

// ---------------- 7) combine: y = g1*e1out + g2*e2out + 0.1*shared -------------
__global__ __launch_bounds__(256) void combine_kernel(const int4* __restrict__ meta_i,
    const f32x2* __restrict__ meta_f, const _Float16* __restrict__ out16,
    float* __restrict__ out)
{
  int n = blockIdx.x;
  int h = threadIdx.x * 4;
  int4 mi = meta_i[n];
  f32x2 mf = meta_f[n];
  f16x4 sv = *(const f16x4*)(out16 + (size_t)(NSLOT + n)*HD + h);
  f32x4 y;
  #pragma unroll
  for (int j = 0; j < 4; ++j) y[j] = 0.1f * (float)sv[j];
  if (mi.y >= 0) {
    f16x4 v = *(const f16x4*)(out16 + (size_t)(mi.x*CAP + mi.y)*HD + h);
    #pragma unroll
    for (int j = 0; j < 4; ++j) y[j] += mf[0] * (float)v[j];
  }
  if (mi.w >= 0) {
    f16x4 v = *(const f16x4*)(out16 + (size_t)(mi.z*CAP + mi.w)*HD + h);
    #pragma unroll
    for (int j = 0; j < 4; ++j) y[j] += mf[1] * (float)v[j];
  }
  *(f32x4*)(out + (size_t)n*HD + h) = y;
}

__global__ void fill_sentinel(float* out, int nelem) {
  int i = blockIdx.x*256 + threadIdx.x;
  if (i < nelem) out[i] = 12345.0f;   // distinctive: means ws_size was too small
}

// ---------------- host ----------------
extern "C" void kernel_launch(void* const* d_in, const int* in_sizes, int n_in,
                              void* d_out, int out_size, void* d_ws, size_t ws_size,
                              hipStream_t stream) {
  const float* x   = (const float*)d_in[0];
  const float* rw  = (const float*)d_in[1];
  const float* w1  = (const float*)d_in[2];
  const float* b1  = (const float*)d_in[3];
  const float* w2  = (const float*)d_in[4];
  const float* b2  = (const float*)d_in[5];
  const float* sw1 = (const float*)d_in[6];
  const float* sb1 = (const float*)d_in[7];
  const float* sw2 = (const float*)d_in[8];
  const float* sb2 = (const float*)d_in[9];
  float* out = (float*)d_out;

  char* p = (char*)d_ws;
  auto alloc = [&](size_t bytes) { char* r = p; p += (bytes + 255) & ~(size_t)255; return r; };
  _Float16* x16  = (_Float16*)alloc((size_t)NTOK*HD*2);
  _Float16* w1t  = (_Float16*)alloc((size_t)NE*FD*HD*2);
  _Float16* w2t  = (_Float16*)alloc((size_t)NE*HD*FD*2);
  _Float16* sw1t = (_Float16*)alloc((size_t)FD*HD*2);
  _Float16* sw2t = (_Float16*)alloc((size_t)HD*FD*2);
  _Float16* mid  = (_Float16*)alloc((size_t)TOTSLOT*FD*2);
  _Float16* o16  = (_Float16*)alloc((size_t)TOTSLOT*HD*2);
  double* logits = (double*)alloc((size_t)NTOK*NE*8);
  int4*   meta_i = (int4*)alloc((size_t)NTOK*16);
  f32x2*  meta_f = (f32x2*)alloc((size_t)NTOK*8);
  int* slot_src  = (int*)alloc((size_t)NSLOT*4);
  int* rows_dev  = (int*)alloc(64);
  size_t need = (size_t)(p - (char*)d_ws);
  if (need > ws_size) {
    fill_sentinel<<<(out_size+255)/256, 256, 0, stream>>>(out, out_size);
    return;
  }

  transpose_cvt<<<4864, 512, 0, stream>>>(w1, w2, sw1, sw2, x, w1t, w2t, sw1t, sw2t, x16);
  router_kernel<<<NTOK/4, 256, 0, stream>>>(x, rw, logits);
  gating_kernel<<<1, 1024, 0, stream>>>(logits, meta_i, meta_f, slot_src, rows_dev);
  gemm_kernel<HD, FD, true><<<112*(FD/128), 256, 0, stream>>>(
      x16, w1t, sw1t, b1, sb1, mid, slot_src, rows_dev);
  gemm_kernel<FD, HD, false><<<112*(HD/128), 256, 0, stream>>>(
      mid, w2t, sw2t, b2, sb2, o16, slot_src, rows_dev);
  combine_kernel<<<NTOK, 256, 0, stream>>>(meta_i, meta_f, o16, out);
}